// Round 4
// baseline (2608.155 us; speedup 1.0000x reference)
//
#include <hip/hip_runtime.h>
#include <math.h>

typedef unsigned short u16;
typedef unsigned int u32;
typedef __attribute__((ext_vector_type(8))) short short8;
typedef __attribute__((ext_vector_type(4))) float f32x4;

#define EPSQ 1e-5f
#define B_ROWS 41472                 // 512*81 tokens
#define Z_ELEMS ((size_t)B_ROWS * 512)

// ---- bf16 helpers (manual RNE) -------------------------------------------
__device__ __forceinline__ u16 f2b(float f) {
  u32 x = __float_as_uint(f);
  u32 r = (x + 0x7fffu + ((x >> 16) & 1u)) >> 16;   // round-to-nearest-even
  return (u16)r;
}
__device__ __forceinline__ float blo(u32 v) { return __uint_as_float(v << 16); }
__device__ __forceinline__ float bhi(u32 v) { return __uint_as_float(v & 0xffff0000u); }
__device__ __forceinline__ u32 pack2(float a, float b) {
  return (u32)f2b(a) | ((u32)f2b(b) << 16);
}

__device__ __forceinline__ float wredMax(float v) {
#pragma unroll
  for (int off = 32; off; off >>= 1) v = fmaxf(v, __shfl_xor(v, off));
  return v;
}
__device__ __forceinline__ float wredSum(float v) {
#pragma unroll
  for (int off = 32; off; off >>= 1) v += __shfl_xor(v, off);
  return v;
}

// ---- weight quantization: per-tensor mean|w| -> ternary ------------------
__global__ __launch_bounds__(256) void wq_sum(const float* __restrict__ w, int n,
                                              float* __restrict__ sum) {
  float acc = 0.f;
  for (int i = blockIdx.x * blockDim.x + threadIdx.x; i < n; i += gridDim.x * blockDim.x)
    acc += fabsf(w[i]);
  acc = wredSum(acc);
  if ((threadIdx.x & 63) == 0) atomicAdd(sum, acc);
}

__global__ __launch_bounds__(256) void wq_quant(const float* __restrict__ w, int n,
                                                const float* __restrict__ sum,
                                                float* __restrict__ mout,
                                                u16* __restrict__ q) {
  const float m = fmaxf(sum[0] / (float)n, EPSQ);
  if (blockIdx.x == 0 && threadIdx.x == 0) mout[0] = m;
  const float s = 1.0f / m;
  for (int i = blockIdx.x * blockDim.x + threadIdx.x; i < n; i += gridDim.x * blockDim.x) {
    float t = rintf(w[i] * s);
    t = fminf(fmaxf(t, -1.f), 1.f);
    q[i] = f2b(t);
  }
}

// ---- act quant of concat([x,y,s]) rows (1536): one 128-thr block per row -
__global__ __launch_bounds__(128) void aq_concat(const float* __restrict__ x,
                                                 const float* __restrict__ y,
                                                 const float* __restrict__ s,
                                                 u16* __restrict__ qx,
                                                 float* __restrict__ dsc, int row0) {
  const int r = blockIdx.x;
  const size_t R = (size_t)(row0 + r);
  const int t = threadIdx.x;
  float4 vx = *(const float4*)(x + R * 512 + t * 4);
  float4 vy = *(const float4*)(y + R * 512 + t * 4);
  float4 vs = *(const float4*)(s + R * 512 + t * 4);
  float mx = fmaxf(fmaxf(fmaxf(fabsf(vx.x), fabsf(vx.y)), fmaxf(fabsf(vx.z), fabsf(vx.w))),
            fmaxf(fmaxf(fmaxf(fabsf(vy.x), fabsf(vy.y)), fmaxf(fabsf(vy.z), fabsf(vy.w))),
                  fmaxf(fmaxf(fabsf(vs.x), fabsf(vs.y)), fmaxf(fabsf(vs.z), fabsf(vs.w)))));
  mx = wredMax(mx);
  __shared__ float red[2];
  if ((t & 63) == 0) red[t >> 6] = mx;
  __syncthreads();
  mx = fmaxf(red[0], red[1]);
  const float m = fmaxf(mx, EPSQ);
  const float scq = 127.f / m;
  if (t == 0) dsc[r] = m * (1.f / 127.f);
  u16* qrow = qx + (size_t)r * 1536;
#define QZ(v) fminf(fmaxf(rintf((v) * scq), -128.f), 127.f)
  *(uint2*)&qrow[t * 4] = make_uint2(pack2(QZ(vx.x), QZ(vx.y)), pack2(QZ(vx.z), QZ(vx.w)));
  *(uint2*)&qrow[512 + t * 4] = make_uint2(pack2(QZ(vy.x), QZ(vy.y)), pack2(QZ(vy.z), QZ(vy.w)));
  *(uint2*)&qrow[1024 + t * 4] = make_uint2(pack2(QZ(vs.x), QZ(vs.y)), pack2(QZ(vs.z), QZ(vs.w)));
#undef QZ
}

// ---- sigmoid mask head ---------------------------------------------------
__global__ __launch_bounds__(256) void bit_mask(const u16* __restrict__ qh,
                                                const float* __restrict__ dsc,
                                                const u16* __restrict__ qwm,
                                                const float* __restrict__ mWp,
                                                float* __restrict__ outp) {
  const int row = blockIdx.x * 4 + (threadIdx.x >> 6);
  const int l = threadIdx.x & 63;
  uint4 av = *(const uint4*)(qh + (size_t)row * 512 + l * 8);
  uint4 wv = *(const uint4*)(qwm + l * 8);
  float acc = blo(av.x) * blo(wv.x) + bhi(av.x) * bhi(wv.x) +
              blo(av.y) * blo(wv.y) + bhi(av.y) * bhi(wv.y) +
              blo(av.z) * blo(wv.z) + bhi(av.z) * bhi(wv.z) +
              blo(av.w) * blo(wv.w) + bhi(av.w) * bhi(wv.w);
  acc = wredSum(acc);
  if (l == 0) {
    float v = acc * dsc[row] * mWp[0];
    outp[row] = 1.f / (1.f + expf(-v));
  }
}

// ---- 128x128 GEMM: C = (A @ W^T) * dA[row] * mW --------------------------
// EPI 0: f32 store.  EPI 3: exact-gelu -> bf16 store + per-row |.| atomicMax.
template <int EPI>
__global__ __launch_bounds__(256) void gemm_bt(const u16* __restrict__ A,
                                               const u16* __restrict__ Bw,
                                               const float* __restrict__ dA,
                                               const float* __restrict__ mWp,
                                               float* __restrict__ Cf,
                                               u16* __restrict__ Cb,
                                               float* __restrict__ rmaxG,
                                               int N, int K, int ldc) {
  __shared__ u16 lA[128 * 64];
  __shared__ u16 lB[128 * 64];
  const int tilesN = N >> 7;
  const int tm = blockIdx.x / tilesN, tn = blockIdx.x - tm * tilesN;
  const int t = threadIdx.x;
  const int w = t >> 6, l = t & 63;
  const int wr = w >> 1, wc = w & 1;
  const int lq = l >> 4, lr = l & 15;

  f32x4 zero = {0.f, 0.f, 0.f, 0.f};
  f32x4 acc[4][4];
#pragma unroll
  for (int m = 0; m < 4; ++m)
#pragma unroll
    for (int n = 0; n < 4; ++n) acc[m][n] = zero;

  const int srow = t >> 3;
  const int scb = t & 7;
  const size_t Abase = (size_t)(tm * 128 + srow) * K + scb * 8;
  const size_t Bbase = (size_t)(tn * 128 + srow) * K + scb * 8;

  for (int k0 = 0; k0 < K; k0 += 64) {
    int4 ra[4], rb[4];
#pragma unroll
    for (int r = 0; r < 4; ++r) {
      ra[r] = *(const int4*)(A + Abase + (size_t)r * 32 * K + k0);
      rb[r] = *(const int4*)(Bw + Bbase + (size_t)r * 32 * K + k0);
    }
    __syncthreads();
#pragma unroll
    for (int r = 0; r < 4; ++r) {
      int row = r * 32 + srow;
      *(int4*)&lA[row * 64 + ((scb ^ (row & 7)) << 3)] = ra[r];
      *(int4*)&lB[row * 64 + ((scb ^ (row & 7)) << 3)] = rb[r];
    }
    __syncthreads();
#pragma unroll
    for (int kk = 0; kk < 2; ++kk) {
      short8 av[4], bv[4];
#pragma unroll
      for (int m = 0; m < 4; ++m) {
        int row = wr * 64 + m * 16 + lr;
        av[m] = *(const short8*)&lA[row * 64 + (((kk * 4 + lq) ^ (row & 7)) << 3)];
      }
#pragma unroll
      for (int n = 0; n < 4; ++n) {
        int row = wc * 64 + n * 16 + lr;
        bv[n] = *(const short8*)&lB[row * 64 + (((kk * 4 + lq) ^ (row & 7)) << 3)];
      }
#pragma unroll
      for (int m = 0; m < 4; ++m)
#pragma unroll
        for (int n = 0; n < 4; ++n)
          acc[m][n] = __builtin_amdgcn_mfma_f32_16x16x32_bf16(av[m], bv[n], acc[m][n], 0, 0, 0);
    }
  }

  const float mw = mWp[0];
#pragma unroll
  for (int m = 0; m < 4; ++m) {
#pragma unroll
    for (int r = 0; r < 4; ++r) {
      const int row = tm * 128 + wr * 64 + m * 16 + lq * 4 + r;
      const float sc = dA[row] * mw;
      float amax = 0.f;
#pragma unroll
      for (int n = 0; n < 4; ++n) {
        const int col = tn * 128 + wc * 64 + n * 16 + lr;
        float v = acc[m][n][r] * sc;
        if constexpr (EPI == 0) {
          Cf[(size_t)row * ldc + col] = v;
        } else {
          v = 0.5f * v * (1.f + erff(v * 0.70710678f));   // exact gelu
          u16 b = f2b(v);
          Cb[(size_t)row * ldc + col] = b;
          amax = fmaxf(amax, fabsf(blo((u32)b)));         // max of stored bf16
        }
      }
      if constexpr (EPI == 3) {
#pragma unroll
        for (int off = 1; off < 16; off <<= 1) amax = fmaxf(amax, __shfl_xor(amax, off));
        if (lr == 0) atomicMax((int*)(rmaxG + row), __float_as_int(amax));
      }
    }
  }
}

// ---- fused full-N (512) GEMM: BM=32, 4 waves, per-row quant epilogue -----
// AQ: A is bf16 gelu values, quantize on-the-fly with rowMax scale (dA=rowMax)
//     else A is pre-quantized ints, dA = per-row dequant scale (m/127).
// RESID: 1 -> h += h0 (read); 0 -> write h0.
// Outputs: qout (bf16 int8 row-quantized), dscOut (= clip(rowmax)/127).
template <int AQ, int RESID>
__global__ __launch_bounds__(256, 2) void gemm_fused(const u16* __restrict__ A,
                                                     const u16* __restrict__ Bw,
                                                     const float* __restrict__ dA,
                                                     const float* __restrict__ mWp,
                                                     float* __restrict__ h0,
                                                     u16* __restrict__ qout,
                                                     float* __restrict__ dscOut,
                                                     int K) {
  __shared__ u16 lA[32 * 64];
  __shared__ u16 lB[512 * 64];
  __shared__ float rmax[128];
  const int tm = blockIdx.x;
  const int t = threadIdx.x;
  const int wc = t >> 6, l = t & 63;
  const int lq = l >> 4, lr = l & 15;

  f32x4 zero = {0.f, 0.f, 0.f, 0.f};
  f32x4 acc[2][8];
#pragma unroll
  for (int m = 0; m < 2; ++m)
#pragma unroll
    for (int n = 0; n < 8; ++n) acc[m][n] = zero;

  const int arow = t >> 3, acb = t & 7;
  const size_t Abase = (size_t)(tm * 32 + arow) * K + acb * 8;
  float scqA = 0.f;
  if (AQ) scqA = 127.f / fmaxf(dA[tm * 32 + arow], EPSQ);

  for (int k0 = 0; k0 < K; k0 += 64) {
    int4 ra = *(const int4*)(A + Abase + k0);
    int4 rb[16];
#pragma unroll
    for (int j = 0; j < 16; ++j) {
      const int idx = j * 256 + t;
      const int brow = idx >> 3, bcb = idx & 7;
      rb[j] = *(const int4*)(Bw + (size_t)brow * K + k0 + bcb * 8);
    }
    if (AQ) {   // quantize 8 bf16 gelu values -> int bf16
      u32* rw = (u32*)&ra;
#pragma unroll
      for (int j = 0; j < 4; ++j) {
        float a0 = fminf(fmaxf(rintf(blo(rw[j]) * scqA), -128.f), 127.f);
        float a1 = fminf(fmaxf(rintf(bhi(rw[j]) * scqA), -128.f), 127.f);
        rw[j] = pack2(a0, a1);
      }
    }
    __syncthreads();
    *(int4*)&lA[arow * 64 + ((acb ^ (arow & 7)) << 3)] = ra;
#pragma unroll
    for (int j = 0; j < 16; ++j) {
      const int idx = j * 256 + t;
      const int brow = idx >> 3, bcb = idx & 7;
      *(int4*)&lB[brow * 64 + ((bcb ^ (brow & 7)) << 3)] = rb[j];
    }
    __syncthreads();
#pragma unroll
    for (int kk = 0; kk < 2; ++kk) {
      short8 av[2], bv[8];
#pragma unroll
      for (int m = 0; m < 2; ++m) {
        int row = m * 16 + lr;
        av[m] = *(const short8*)&lA[row * 64 + (((kk * 4 + lq) ^ (row & 7)) << 3)];
      }
#pragma unroll
      for (int n = 0; n < 8; ++n) {
        int row = wc * 128 + n * 16 + lr;
        bv[n] = *(const short8*)&lB[row * 64 + (((kk * 4 + lq) ^ (row & 7)) << 3)];
      }
#pragma unroll
      for (int m = 0; m < 2; ++m)
#pragma unroll
        for (int n = 0; n < 8; ++n)
          acc[m][n] = __builtin_amdgcn_mfma_f32_16x16x32_bf16(av[m], bv[n], acc[m][n], 0, 0, 0);
    }
  }

  // ---- epilogue: h = acc*sc (+h0) ; per-row absmax over 512 ; quantize ---
  const float mw = mWp[0];
#pragma unroll
  for (int m = 0; m < 2; ++m) {
#pragma unroll
    for (int rr = 0; rr < 4; ++rr) {
      const int rloc = m * 16 + lq * 4 + rr;
      const int grow = tm * 32 + rloc;
      float da = AQ ? (fmaxf(dA[grow], EPSQ) * (1.f / 127.f)) : dA[grow];
      const float sc = da * mw;
      float amax = 0.f;
#pragma unroll
      for (int n = 0; n < 8; ++n) {
        const int col = wc * 128 + n * 16 + lr;
        float v = acc[m][n][rr] * sc;
        if (RESID) v += h0[(size_t)grow * 512 + col];
        else h0[(size_t)grow * 512 + col] = v;
        acc[m][n][rr] = v;
        amax = fmaxf(amax, fabsf(v));
      }
#pragma unroll
      for (int off = 1; off < 16; off <<= 1) amax = fmaxf(amax, __shfl_xor(amax, off));
      if (lr == 0) rmax[wc * 32 + rloc] = amax;
    }
  }
  __syncthreads();
#pragma unroll
  for (int m = 0; m < 2; ++m) {
#pragma unroll
    for (int rr = 0; rr < 4; ++rr) {
      const int rloc = m * 16 + lq * 4 + rr;
      const int grow = tm * 32 + rloc;
      float mx = fmaxf(fmaxf(rmax[rloc], rmax[32 + rloc]),
                       fmaxf(rmax[64 + rloc], rmax[96 + rloc]));
      const float m2 = fmaxf(mx, EPSQ);
      const float sq = 127.f / m2;
      if (wc == 0 && lr == 0) dscOut[grow] = m2 * (1.f / 127.f);
#pragma unroll
      for (int n = 0; n < 8; ++n) {
        const int col = wc * 128 + n * 16 + lr;
        float q = fminf(fmaxf(rintf(acc[m][n][rr] * sq), -128.f), 127.f);
        qout[(size_t)grow * 512 + col] = f2b(q);
      }
    }
  }
}

extern "C" void kernel_launch(void* const* d_in, const int* in_sizes, int n_in,
                              void* d_out, int out_size, void* d_ws, size_t ws_size,
                              hipStream_t stream) {
  const float* x = (const float*)d_in[0];
  const float* y = (const float*)d_in[1];
  const float* sp = (const float*)d_in[2];
  const float* Win = (const float*)d_in[3];
  const float* Wf1 = (const float*)d_in[4];
  const float* Wf2 = (const float*)d_in[5];
  const float* Wz = (const float*)d_in[6];
  const float* Wm = (const float*)d_in[7];
  float* out = (float*)d_out;

  const int TILES = B_ROWS / 128;     // 324
  char* p = (char*)d_ws;
  float* wsum = (float*)p; p += 256;
  float* mW = (float*)p; p += 256;
  u16* qWin = (u16*)p; p += (size_t)512 * 1536 * 2;
  u16* qWf1 = (u16*)p; p += (size_t)2048 * 512 * 2;
  u16* qWf2 = (u16*)p; p += (size_t)512 * 2048 * 2;
  u16* qWz = (u16*)p; p += (size_t)512 * 512 * 2;
  u16* qWm = (u16*)p; p += 1024;
  const size_t fixedB = (size_t)(p - (char*)d_ws);

  // per-row bytes: qx 3072 + d1 4 + h0 2048 + qh 1024 + dscH 4 + g 4096
  //              + rmG 4 + qh2 1024 + dsc2 4 = 11280
  int Tc = 1;
  for (int nch = 1; nch <= TILES; ++nch) {
    int tc = (TILES + nch - 1) / nch;
    if (fixedB + (size_t)tc * 128 * 11280 + 4096 <= ws_size) { Tc = tc; break; }
  }
  const size_t McMax = (size_t)Tc * 128;
  u16* qx = (u16*)p; p += McMax * 1536 * 2;
  float* d1 = (float*)p; p += McMax * 4;
  float* h0 = (float*)p; p += McMax * 512 * 4;
  u16* qh = (u16*)p; p += McMax * 512 * 2;
  float* dscH = (float*)p; p += McMax * 4;
  u16* g = (u16*)p; p += McMax * 2048 * 2;
  float* rmG = (float*)p; p += McMax * 4;
  u16* qh2 = (u16*)p; p += McMax * 512 * 2;
  float* dsc2 = (float*)p; p += McMax * 4;

  hipMemsetAsync(wsum, 0, 8 * sizeof(float), stream);
  wq_sum<<<64, 256, 0, stream>>>(Win, 512 * 1536, wsum + 0);
  wq_sum<<<64, 256, 0, stream>>>(Wf1, 2048 * 512, wsum + 1);
  wq_sum<<<64, 256, 0, stream>>>(Wf2, 512 * 2048, wsum + 2);
  wq_sum<<<64, 256, 0, stream>>>(Wz, 512 * 512, wsum + 3);
  wq_sum<<<8, 256, 0, stream>>>(Wm, 512, wsum + 4);
  wq_quant<<<64, 256, 0, stream>>>(Win, 512 * 1536, wsum + 0, mW + 0, qWin);
  wq_quant<<<64, 256, 0, stream>>>(Wf1, 2048 * 512, wsum + 1, mW + 1, qWf1);
  wq_quant<<<64, 256, 0, stream>>>(Wf2, 512 * 2048, wsum + 2, mW + 2, qWf2);
  wq_quant<<<16, 256, 0, stream>>>(Wz, 512 * 512, wsum + 3, mW + 3, qWz);
  wq_quant<<<2, 256, 0, stream>>>(Wm, 512, wsum + 4, mW + 4, qWm);

  for (int c0 = 0; c0 < TILES; c0 += Tc) {
    const int tiles = (TILES - c0 < Tc) ? (TILES - c0) : Tc;
    const int Mc = tiles * 128;
    const int row0 = c0 * 128;
    hipMemsetAsync(rmG, 0, (size_t)Mc * 4, stream);
    aq_concat<<<Mc, 128, 0, stream>>>(x, y, sp, qx, d1, row0);
    gemm_fused<0, 0><<<Mc / 32, 256, 0, stream>>>(qx, qWin, d1, mW + 0, h0, qh, dscH, 1536);
    gemm_bt<3><<<tiles * 16, 256, 0, stream>>>(qh, qWf1, dscH, mW + 1, nullptr, g, rmG,
                                               2048, 512, 2048);
    gemm_fused<1, 1><<<Mc / 32, 256, 0, stream>>>(g, qWf2, rmG, mW + 2, h0, qh2, dsc2, 2048);
    gemm_bt<0><<<tiles * 4, 256, 0, stream>>>(qh2, qWz, dsc2, mW + 3,
                                              out + (size_t)row0 * 512, nullptr, nullptr,
                                              512, 512, 512);
    bit_mask<<<Mc / 4, 256, 0, stream>>>(qh2, dsc2, qWm, mW + 4, out + Z_ELEMS + row0);
  }
}

// Round 6
// 2050.219 us; speedup vs baseline: 1.2721x; 1.2721x over previous
//
#include <hip/hip_runtime.h>
#include <math.h>

typedef unsigned short u16;
typedef unsigned int u32;
typedef __attribute__((ext_vector_type(8))) short short8;
typedef __attribute__((ext_vector_type(4))) float f32x4;

#define EPSQ 1e-5f
#define B_ROWS 41472                 // 512*81 tokens
#define Z_ELEMS ((size_t)B_ROWS * 512)

// ---- bf16 helpers (manual RNE) -------------------------------------------
__device__ __forceinline__ u16 f2b(float f) {
  u32 x = __float_as_uint(f);
  u32 r = (x + 0x7fffu + ((x >> 16) & 1u)) >> 16;   // round-to-nearest-even
  return (u16)r;
}
__device__ __forceinline__ float blo(u32 v) { return __uint_as_float(v << 16); }
__device__ __forceinline__ float bhi(u32 v) { return __uint_as_float(v & 0xffff0000u); }
__device__ __forceinline__ u32 pack2(float a, float b) {
  return (u32)f2b(a) | ((u32)f2b(b) << 16);
}

__device__ __forceinline__ float wredMax(float v) {
#pragma unroll
  for (int off = 32; off; off >>= 1) v = fmaxf(v, __shfl_xor(v, off));
  return v;
}
__device__ __forceinline__ float wredSum(float v) {
#pragma unroll
  for (int off = 32; off; off >>= 1) v += __shfl_xor(v, off);
  return v;
}

// ---- weight quantization: per-tensor mean|w| -> ternary ------------------
__global__ __launch_bounds__(256) void wq_sum(const float* __restrict__ w, int n,
                                              float* __restrict__ sum) {
  float acc = 0.f;
  for (int i = blockIdx.x * blockDim.x + threadIdx.x; i < n; i += gridDim.x * blockDim.x)
    acc += fabsf(w[i]);
  acc = wredSum(acc);
  if ((threadIdx.x & 63) == 0) atomicAdd(sum, acc);
}

__global__ __launch_bounds__(256) void wq_quant(const float* __restrict__ w, int n,
                                                const float* __restrict__ sum,
                                                float* __restrict__ mout,
                                                u16* __restrict__ q) {
  const float m = fmaxf(sum[0] / (float)n, EPSQ);
  if (blockIdx.x == 0 && threadIdx.x == 0) mout[0] = m;
  const float s = 1.0f / m;
  for (int i = blockIdx.x * blockDim.x + threadIdx.x; i < n; i += gridDim.x * blockDim.x) {
    float t = rintf(w[i] * s);
    t = fminf(fmaxf(t, -1.f), 1.f);
    q[i] = f2b(t);
  }
}

// ---- act quant of concat([x,y,s]) rows (1536): one 128-thr block per row -
__global__ __launch_bounds__(128) void aq_concat(const float* __restrict__ x,
                                                 const float* __restrict__ y,
                                                 const float* __restrict__ s,
                                                 u16* __restrict__ qx,
                                                 float* __restrict__ dsc, int row0) {
  const int r = blockIdx.x;
  const size_t R = (size_t)(row0 + r);
  const int t = threadIdx.x;
  float4 vx = *(const float4*)(x + R * 512 + t * 4);
  float4 vy = *(const float4*)(y + R * 512 + t * 4);
  float4 vs = *(const float4*)(s + R * 512 + t * 4);
  float mx = fmaxf(fmaxf(fmaxf(fabsf(vx.x), fabsf(vx.y)), fmaxf(fabsf(vx.z), fabsf(vx.w))),
            fmaxf(fmaxf(fmaxf(fabsf(vy.x), fabsf(vy.y)), fmaxf(fabsf(vy.z), fabsf(vy.w))),
                  fmaxf(fmaxf(fabsf(vs.x), fabsf(vs.y)), fmaxf(fabsf(vs.z), fabsf(vs.w)))));
  mx = wredMax(mx);
  __shared__ float red[2];
  if ((t & 63) == 0) red[t >> 6] = mx;
  __syncthreads();
  mx = fmaxf(red[0], red[1]);
  const float m = fmaxf(mx, EPSQ);
  const float scq = 127.f / m;
  if (t == 0) dsc[r] = m * (1.f / 127.f);
  u16* qrow = qx + (size_t)r * 1536;
#define QZ(v) fminf(fmaxf(rintf((v) * scq), -128.f), 127.f)
  *(uint2*)&qrow[t * 4] = make_uint2(pack2(QZ(vx.x), QZ(vx.y)), pack2(QZ(vx.z), QZ(vx.w)));
  *(uint2*)&qrow[512 + t * 4] = make_uint2(pack2(QZ(vy.x), QZ(vy.y)), pack2(QZ(vy.z), QZ(vy.w)));
  *(uint2*)&qrow[1024 + t * 4] = make_uint2(pack2(QZ(vs.x), QZ(vs.y)), pack2(QZ(vs.z), QZ(vs.w)));
#undef QZ
}

// ---- act quant of f32 rows of 512 (one wave per row) ---------------------
__global__ __launch_bounds__(256) void aq_row512(const float* __restrict__ src,
                                                 u16* __restrict__ q,
                                                 float* __restrict__ dsc) {
  const int row = blockIdx.x * 4 + (threadIdx.x >> 6);
  const int l = threadIdx.x & 63;
  const float* pr = src + (size_t)row * 512 + l * 8;
  float4 v0 = *(const float4*)pr;
  float4 v1 = *(const float4*)(pr + 4);
  float mx = fmaxf(fmaxf(fmaxf(fabsf(v0.x), fabsf(v0.y)), fmaxf(fabsf(v0.z), fabsf(v0.w))),
                   fmaxf(fmaxf(fabsf(v1.x), fabsf(v1.y)), fmaxf(fabsf(v1.z), fabsf(v1.w))));
  mx = wredMax(mx);
  const float m = fmaxf(mx, EPSQ);
  const float scq = 127.f / m;
  if (l == 0) dsc[row] = m * (1.f / 127.f);
#define QZ(v) fminf(fmaxf(rintf((v) * scq), -128.f), 127.f)
  uint4 o = make_uint4(pack2(QZ(v0.x), QZ(v0.y)), pack2(QZ(v0.z), QZ(v0.w)),
                       pack2(QZ(v1.x), QZ(v1.y)), pack2(QZ(v1.z), QZ(v1.w)));
#undef QZ
  *(uint4*)(q + (size_t)row * 512 + l * 8) = o;
}

// ---- sigmoid mask head ---------------------------------------------------
__global__ __launch_bounds__(256) void bit_mask(const u16* __restrict__ qh,
                                                const float* __restrict__ dsc,
                                                const u16* __restrict__ qwm,
                                                const float* __restrict__ mWp,
                                                float* __restrict__ outp) {
  const int row = blockIdx.x * 4 + (threadIdx.x >> 6);
  const int l = threadIdx.x & 63;
  uint4 av = *(const uint4*)(qh + (size_t)row * 512 + l * 8);
  uint4 wv = *(const uint4*)(qwm + l * 8);
  float acc = blo(av.x) * blo(wv.x) + bhi(av.x) * bhi(wv.x) +
              blo(av.y) * blo(wv.y) + bhi(av.y) * bhi(wv.y) +
              blo(av.z) * blo(wv.z) + bhi(av.z) * bhi(wv.z) +
              blo(av.w) * blo(wv.w) + bhi(av.w) * bhi(wv.w);
  acc = wredSum(acc);
  if (l == 0) {
    float v = acc * dsc[row] * mWp[0];
    outp[row] = 1.f / (1.f + expf(-v));
  }
}

// ---- 128x128 GEMM: C = (A @ W^T) * dA[row] * mW --------------------------
// EPI 0: f32 store.
// EPI 2: f32 in-place residual (Cf[ix] += v).
// EPI 3: exact-gelu -> bf16 store + per-row |.| atomicMax into rmaxG.
// AQ  1: A is bf16 real values; quantize during staging with 127/max(dA[row],EPS);
//        epilogue dequant uses max(dA[row],EPS)/127. AQ 0: A pre-quantized, dA = scale.
template <int EPI, int AQ>
__global__ __launch_bounds__(256) void gemm_bt(const u16* __restrict__ A,
                                               const u16* __restrict__ Bw,
                                               const float* __restrict__ dA,
                                               const float* __restrict__ mWp,
                                               float* __restrict__ Cf,
                                               u16* __restrict__ Cb,
                                               float* __restrict__ rmaxG,
                                               int N, int K, int ldc) {
  __shared__ u16 lA[128 * 64];
  __shared__ u16 lB[128 * 64];
  const int tilesN = N >> 7;
  const int tm = blockIdx.x / tilesN, tn = blockIdx.x - tm * tilesN;
  const int t = threadIdx.x;
  const int w = t >> 6, l = t & 63;
  const int wr = w >> 1, wc = w & 1;
  const int lq = l >> 4, lr = l & 15;

  f32x4 zero = {0.f, 0.f, 0.f, 0.f};
  f32x4 acc[4][4];
#pragma unroll
  for (int m = 0; m < 4; ++m)
#pragma unroll
    for (int n = 0; n < 4; ++n) acc[m][n] = zero;

  const int srow = t >> 3;
  const int scb = t & 7;
  const size_t Abase = (size_t)(tm * 128 + srow) * K + scb * 8;
  const size_t Bbase = (size_t)(tn * 128 + srow) * K + scb * 8;

  float scq[4];
  if (AQ) {
#pragma unroll
    for (int r = 0; r < 4; ++r)
      scq[r] = 127.f / fmaxf(dA[tm * 128 + r * 32 + srow], EPSQ);
  }

  for (int k0 = 0; k0 < K; k0 += 64) {
    int4 ra[4], rb[4];
#pragma unroll
    for (int r = 0; r < 4; ++r) {
      ra[r] = *(const int4*)(A + Abase + (size_t)r * 32 * K + k0);
      rb[r] = *(const int4*)(Bw + Bbase + (size_t)r * 32 * K + k0);
    }
    if (AQ) {   // quantize 8 bf16 values per staged row -> int bf16
#pragma unroll
      for (int r = 0; r < 4; ++r) {
        u32* rw = (u32*)&ra[r];
#pragma unroll
        for (int j = 0; j < 4; ++j) {
          float a0 = fminf(fmaxf(rintf(blo(rw[j]) * scq[r]), -128.f), 127.f);
          float a1 = fminf(fmaxf(rintf(bhi(rw[j]) * scq[r]), -128.f), 127.f);
          rw[j] = pack2(a0, a1);
        }
      }
    }
    __syncthreads();
#pragma unroll
    for (int r = 0; r < 4; ++r) {
      int row = r * 32 + srow;
      *(int4*)&lA[row * 64 + ((scb ^ (row & 7)) << 3)] = ra[r];
      *(int4*)&lB[row * 64 + ((scb ^ (row & 7)) << 3)] = rb[r];
    }
    __syncthreads();
#pragma unroll
    for (int kk = 0; kk < 2; ++kk) {
      short8 av[4], bv[4];
#pragma unroll
      for (int m = 0; m < 4; ++m) {
        int row = wr * 64 + m * 16 + lr;
        av[m] = *(const short8*)&lA[row * 64 + (((kk * 4 + lq) ^ (row & 7)) << 3)];
      }
#pragma unroll
      for (int n = 0; n < 4; ++n) {
        int row = wc * 64 + n * 16 + lr;
        bv[n] = *(const short8*)&lB[row * 64 + (((kk * 4 + lq) ^ (row & 7)) << 3)];
      }
#pragma unroll
      for (int m = 0; m < 4; ++m)
#pragma unroll
        for (int n = 0; n < 4; ++n)
          acc[m][n] = __builtin_amdgcn_mfma_f32_16x16x32_bf16(av[m], bv[n], acc[m][n], 0, 0, 0);
    }
  }

  const float mw = mWp[0];
#pragma unroll
  for (int m = 0; m < 4; ++m) {
#pragma unroll
    for (int r = 0; r < 4; ++r) {
      const int row = tm * 128 + wr * 64 + m * 16 + lq * 4 + r;
      const float da = AQ ? (fmaxf(dA[row], EPSQ) * (1.f / 127.f)) : dA[row];
      const float sc = da * mw;
      float amax = 0.f;
#pragma unroll
      for (int n = 0; n < 4; ++n) {
        const int col = tn * 128 + wc * 64 + n * 16 + lr;
        float v = acc[m][n][r] * sc;
        if constexpr (EPI == 0) {
          Cf[(size_t)row * ldc + col] = v;
        } else if constexpr (EPI == 2) {
          size_t ix = (size_t)row * ldc + col;
          Cf[ix] += v;                                    // in-place residual
        } else {
          v = 0.5f * v * (1.f + erff(v * 0.70710678f));   // exact gelu
          u16 b = f2b(v);
          Cb[(size_t)row * ldc + col] = b;
          amax = fmaxf(amax, fabsf(blo((u32)b)));         // max of stored bf16
        }
      }
      if constexpr (EPI == 3) {
#pragma unroll
        for (int off = 1; off < 16; off <<= 1) amax = fmaxf(amax, __shfl_xor(amax, off));
        if (lr == 0) atomicMax((int*)(rmaxG + row), __float_as_int(amax));
      }
    }
  }
}

extern "C" void kernel_launch(void* const* d_in, const int* in_sizes, int n_in,
                              void* d_out, int out_size, void* d_ws, size_t ws_size,
                              hipStream_t stream) {
  const float* x = (const float*)d_in[0];
  const float* y = (const float*)d_in[1];
  const float* sp = (const float*)d_in[2];
  const float* Win = (const float*)d_in[3];
  const float* Wf1 = (const float*)d_in[4];
  const float* Wf2 = (const float*)d_in[5];
  const float* Wz = (const float*)d_in[6];
  const float* Wm = (const float*)d_in[7];
  float* out = (float*)d_out;

  const int TILES = B_ROWS / 128;     // 324
  char* p = (char*)d_ws;
  float* wsum = (float*)p; p += 256;
  float* mW = (float*)p; p += 256;
  u16* qWin = (u16*)p; p += (size_t)512 * 1536 * 2;
  u16* qWf1 = (u16*)p; p += (size_t)2048 * 512 * 2;
  u16* qWf2 = (u16*)p; p += (size_t)512 * 2048 * 2;
  u16* qWz = (u16*)p; p += (size_t)512 * 512 * 2;
  u16* qWm = (u16*)p; p += 1024;
  const size_t fixedB = (size_t)(p - (char*)d_ws);

  // per-row bytes: qx 3072 + d1 4 + h 2048 + qh 1024 + d2 4 + g 4096
  //              + rmG 4 + qh2 1024 + d3 4 = 11280
  // L3-blocking: cap chunk at 54 tiles (6912 rows, ~78 MB working set -> L3-resident)
  int Tc = 1;
  for (int nch = 6; nch <= TILES; ++nch) {
    int tc = (TILES + nch - 1) / nch;
    if (fixedB + (size_t)tc * 128 * 11280 + 4096 <= ws_size) { Tc = tc; break; }
  }
  const size_t McMax = (size_t)Tc * 128;
  u16* qx = (u16*)p; p += McMax * 1536 * 2;
  float* d1 = (float*)p; p += McMax * 4;
  float* h = (float*)p; p += McMax * 512 * 4;
  u16* qh = (u16*)p; p += McMax * 512 * 2;
  float* d2 = (float*)p; p += McMax * 4;
  u16* g = (u16*)p; p += McMax * 2048 * 2;
  float* rmG = (float*)p; p += McMax * 4;
  u16* qh2 = (u16*)p; p += McMax * 512 * 2;
  float* d3 = (float*)p; p += McMax * 4;

  hipMemsetAsync(wsum, 0, 8 * sizeof(float), stream);
  wq_sum<<<64, 256, 0, stream>>>(Win, 512 * 1536, wsum + 0);
  wq_sum<<<64, 256, 0, stream>>>(Wf1, 2048 * 512, wsum + 1);
  wq_sum<<<64, 256, 0, stream>>>(Wf2, 512 * 2048, wsum + 2);
  wq_sum<<<64, 256, 0, stream>>>(Wz, 512 * 512, wsum + 3);
  wq_sum<<<8, 256, 0, stream>>>(Wm, 512, wsum + 4);
  wq_quant<<<64, 256, 0, stream>>>(Win, 512 * 1536, wsum + 0, mW + 0, qWin);
  wq_quant<<<64, 256, 0, stream>>>(Wf1, 2048 * 512, wsum + 1, mW + 1, qWf1);
  wq_quant<<<64, 256, 0, stream>>>(Wf2, 512 * 2048, wsum + 2, mW + 2, qWf2);
  wq_quant<<<16, 256, 0, stream>>>(Wz, 512 * 512, wsum + 3, mW + 3, qWz);
  wq_quant<<<2, 256, 0, stream>>>(Wm, 512, wsum + 4, mW + 4, qWm);

  for (int c0 = 0; c0 < TILES; c0 += Tc) {
    const int tiles = (TILES - c0 < Tc) ? (TILES - c0) : Tc;
    const int Mc = tiles * 128;
    const int row0 = c0 * 128;
    hipMemsetAsync(rmG, 0, (size_t)Mc * 4, stream);
    aq_concat<<<Mc, 128, 0, stream>>>(x, y, sp, qx, d1, row0);
    // proj_in: h = (qx @ Win^T) * d1 * mW0           [N=512, K=1536]
    gemm_bt<0, 0><<<tiles * 4, 256, 0, stream>>>(qx, qWin, d1, mW + 0, h, nullptr, nullptr,
                                                 512, 1536, 512);
    aq_row512<<<Mc / 4, 256, 0, stream>>>(h, qh, d2);
    // fc1: g = gelu((qh @ Wf1^T) * d2 * mW1) bf16 + rmG  [N=2048, K=512]
    gemm_bt<3, 0><<<tiles * 16, 256, 0, stream>>>(qh, qWf1, d2, mW + 1, nullptr, g, rmG,
                                                  2048, 512, 2048);
    // fc2: h += (quant(g) @ Wf2^T) * (rmG/127) * mW2     [N=512, K=2048]
    gemm_bt<2, 1><<<tiles * 4, 256, 0, stream>>>(g, qWf2, rmG, mW + 2, h, nullptr, nullptr,
                                                 512, 2048, 512);
    aq_row512<<<Mc / 4, 256, 0, stream>>>(h, qh2, d3);
    // z: out = (qh2 @ Wz^T) * d3 * mW3                   [N=512, K=512]
    gemm_bt<0, 0><<<tiles * 4, 256, 0, stream>>>(qh2, qWz, d3, mW + 3,
                                                 out + (size_t)row0 * 512, nullptr, nullptr,
                                                 512, 512, 512);
    bit_mask<<<Mc / 4, 256, 0, stream>>>(qh2, d3, qWm, mW + 4, out + Z_ELEMS + row0);
  }
}